// Round 1
// baseline (416.917 us; speedup 1.0000x reference)
//
#include <hip/hip_runtime.h>

__device__ __forceinline__ float crelu(float v) {
    return fminf(1.0f, fmaxf(-1.0f, v));
}

#define BT 32
#define ROW 385

__global__ __launch_bounds__(256, 2)
void lila_fused(const float* __restrict__ inp,
                const float* __restrict__ W1, const float* __restrict__ b1,
                const float* __restrict__ W2, const float* __restrict__ b2,
                const float* __restrict__ W3, const float* __restrict__ b3,
                const float* __restrict__ E1, const float* __restrict__ c1,
                const float* __restrict__ E2, const float* __restrict__ c2,
                const float* __restrict__ E3, const float* __restrict__ c3,
                float* __restrict__ out)
{
    __shared__ float s_inp[BT * ROW];   // 49280 B staged input rows
    __shared__ float s_vis[BT * 37];    // per-(b) vision vector (36 v's + center)
    __shared__ float s_g1[BT * 17];     // stride 17: conflict-free
    __shared__ float s_g2[BT * 17];

    const int tid = threadIdx.x;
    const long long b0 = (long long)blockIdx.x * BT;

    // ---- stage 32 input rows into LDS (contiguous float4 copy) ----
    {
        const float4* g = (const float4*)(inp + b0 * ROW);
        float4* s = (float4*)s_inp;
        for (int i = tid; i < BT * ROW / 4; i += 256)
            s[i] = g[i];
    }
    __syncthreads();

    // ---- patch MLP: 54 -> 8 -> 8 -> 1, one thread per (b, patch) ----
    for (int task = tid; task < BT * 36; task += 256) {
        unsigned b = (unsigned)task / 36u;
        unsigned p = (unsigned)task - b * 36u;
        unsigned x = p / 6u, y = p - x * 6u;
        const float* base = s_inp + b * ROW + x * 48 + y * 6;

        float acc[8];
        #pragma unroll
        for (int o = 0; o < 8; ++o) acc[o] = b1[o];

        #pragma unroll
        for (int ox = 0; ox < 3; ++ox)
        #pragma unroll
        for (int oy = 0; oy < 3; ++oy) {
            const float* r = base + ox * 48 + oy * 6;
            const float* w = W1 + (ox * 3 + oy) * 6 * 8;   // uniform -> s_load
            #pragma unroll
            for (int c = 0; c < 6; ++c) {
                float xv = r[c];
                #pragma unroll
                for (int o = 0; o < 8; ++o)
                    acc[o] = fmaf(xv, w[c * 8 + o], acc[o]);
            }
        }

        float h[8];
        #pragma unroll
        for (int o = 0; o < 8; ++o) h[o] = crelu(acc[o]);

        float a2[8];
        #pragma unroll
        for (int o = 0; o < 8; ++o) a2[o] = b2[o];
        #pragma unroll
        for (int i = 0; i < 8; ++i) {
            #pragma unroll
            for (int o = 0; o < 8; ++o)
                a2[o] = fmaf(h[i], W2[i * 8 + o], a2[o]);
        }

        float v = b3[0];
        #pragma unroll
        for (int i = 0; i < 8; ++i) v = fmaf(crelu(a2[i]), W3[i], v);
        s_vis[b * 37 + p] = crelu(v);
    }
    if (tid < BT) s_vis[tid * 37 + 36] = s_inp[tid * ROW + 384];
    __syncthreads();

    // ---- vision layer 1: 37 -> 16, thread = (b, o) ----
    #pragma unroll
    for (int rep = 0; rep < 2; ++rep) {
        int t = tid + rep * 256;
        int b = t & 31, o = t >> 5;          // rep0: o 0..7, rep1: o 8..15
        float a = c1[o];
        #pragma unroll
        for (int f = 0; f < 37; ++f)
            a = fmaf(s_vis[b * 37 + f], E1[f * 16 + o], a);
        s_g1[b * 17 + o] = crelu(a);
    }
    __syncthreads();

    // ---- vision layer 2: 16 -> 16 ----
    #pragma unroll
    for (int rep = 0; rep < 2; ++rep) {
        int t = tid + rep * 256;
        int b = t & 31, o = t >> 5;
        float a = c2[o];
        #pragma unroll
        for (int f = 0; f < 16; ++f)
            a = fmaf(s_g1[b * 17 + f], E2[f * 16 + o], a);
        s_g2[b * 17 + o] = crelu(a);
    }
    __syncthreads();

    // ---- output: 16 -> 1 ----
    if (tid < BT) {
        float a = c3[0];
        #pragma unroll
        for (int f = 0; f < 16; ++f)
            a = fmaf(s_g2[tid * 17 + f], E3[f], a);
        out[b0 + tid] = crelu(a);
    }
}

extern "C" void kernel_launch(void* const* d_in, const int* in_sizes, int n_in,
                              void* d_out, int out_size, void* d_ws, size_t ws_size,
                              hipStream_t stream)
{
    const float* inp = (const float*)d_in[0];
    const float* W1  = (const float*)d_in[1];
    const float* b1  = (const float*)d_in[2];
    const float* W2  = (const float*)d_in[3];
    const float* b2  = (const float*)d_in[4];
    const float* W3  = (const float*)d_in[5];
    const float* b3  = (const float*)d_in[6];
    const float* E1  = (const float*)d_in[7];
    const float* c1  = (const float*)d_in[8];
    const float* E2  = (const float*)d_in[9];
    const float* c2  = (const float*)d_in[10];
    const float* E3  = (const float*)d_in[11];
    const float* c3  = (const float*)d_in[12];
    float* out = (float*)d_out;

    int B = in_sizes[0] / ROW;           // 131072
    int grid = B / BT;                   // 4096 blocks
    lila_fused<<<grid, 256, 0, stream>>>(inp, W1, b1, W2, b2, W3, b3,
                                         E1, c1, E2, c2, E3, c3, out);
}

// Round 2
// 349.144 us; speedup vs baseline: 1.1941x; 1.1941x over previous
//
#include <hip/hip_runtime.h>

typedef __attribute__((ext_vector_type(8))) short short8;
typedef __attribute__((ext_vector_type(4))) float float4v;

__device__ __forceinline__ float crelu(float v) {
    return fminf(1.0f, fmaxf(-1.0f, v));
}
// fp32 -> bf16 bits, round-to-nearest-even (inputs finite)
__device__ __forceinline__ ushort f2bf(float v) {
    uint u = __float_as_uint(v);
    u += 0x7fffu + ((u >> 16) & 1u);
    return (ushort)(u >> 16);
}

#define ROW 385
#define BT 32
#define BS 388                      // board row stride in bf16 elems (even!)
#define BOARD_ELEMS (BT * BS)       // 12416
#define BOARD_TOTAL (BOARD_ELEMS + 64)

__global__ __launch_bounds__(256, 3)
void lila_mfma(const float* __restrict__ inp,
               const float* __restrict__ W1, const float* __restrict__ b1,
               const float* __restrict__ W2, const float* __restrict__ b2,
               const float* __restrict__ W3, const float* __restrict__ b3,
               const float* __restrict__ E1, const float* __restrict__ c1,
               const float* __restrict__ E2, const float* __restrict__ c2,
               const float* __restrict__ E3, const float* __restrict__ c3,
               float* __restrict__ out)
{
    __shared__ __align__(16) ushort s_board[BOARD_TOTAL]; // 24960 B
    __shared__ __align__(16) ushort s_h[BT * 36 * 8];     // 18432 B
    __shared__ float s_vis[BT * 37];                      // 4736 B, stride 37: conflict-free
    __shared__ float s_cen[BT];
    __shared__ float s_g1[BT * 17];
    __shared__ float s_g2[BT * 17];

    const int tid  = threadIdx.x;
    const int lane = tid & 63;
    const int wv   = tid >> 6;
    const int quad = lane >> 4;
    const int nn   = tid & 15;
    const int m0   = quad * 8;
    const long long b0 = (long long)blockIdx.x * BT;

    // ---- B fragments for layer-1 MFMA (K runs of 18 zero-padded to 32) ----
    // B[k][n]: n = lane&15, k = quad*8 + j. n>=8 or k>=18 -> 0.
    short8 bfr[3];
    #pragma unroll
    for (int r = 0; r < 3; ++r) {
        #pragma unroll
        for (int j = 0; j < 8; ++j) {
            int k = m0 + j;
            float w = (k < 18 && nn < 8) ? W1[(r * 18 + k) * 8 + nn] : 0.0f;
            bfr[r][j] = (short)f2bf(w);
        }
    }
    const float bias1 = (nn < 8) ? b1[nn] : 0.0f;

    // ---- stage 32 input rows -> bf16 board in LDS ----
    #pragma unroll 1
    for (int rr = 0; rr < 8; ++rr) {
        int row = wv * 8 + rr;
        const float* gr = inp + (b0 + row) * ROW;
        ushort* br = s_board + row * BS;
        #pragma unroll
        for (int s = 0; s < 6; ++s)
            br[lane + 64 * s] = f2bf(gr[lane + 64 * s]);
        if (lane == 0) s_cen[row] = gr[384];
        if (lane < 4)  br[384 + lane] = 0;   // zero row pad (NaN-safety for overreads)
    }
    if (tid < 64) s_board[BOARD_ELEMS + tid] = 0; // zero tail pad
    __syncthreads();

    // ---- phase 1: layer 1 (54->8) via bf16 MFMA, 72 tiles of 16 tasks ----
    #pragma unroll 1
    for (int t = wv; t < 72; t += 4) {
        int task = t * 16 + nn;                 // A row m = lane&15
        uint b = (uint)task / 36u;
        uint p = (uint)task - 36u * b;
        uint x = p / 6u;
        uint y = p - 6u * x;
        // run r starts at board elem b*BS + (x+r)*48 + 6y; lane reads k = m0+j
        const uint* bp = (const uint*)(s_board + b * BS + x * 48 + 6 * y + m0);
        union { uint u[4]; short8 s; } a0, a1, a2;
        #pragma unroll
        for (int q = 0; q < 4; ++q) {
            a0.u[q] = bp[q];        // run 0: +0 elems
            a1.u[q] = bp[24 + q];   // run 1: +48 elems
            a2.u[q] = bp[48 + q];   // run 2: +96 elems
        }
        float4v acc = { bias1, bias1, bias1, bias1 };
        acc = __builtin_amdgcn_mfma_f32_16x16x32_bf16(a0.s, bfr[0], acc, 0, 0, 0);
        acc = __builtin_amdgcn_mfma_f32_16x16x32_bf16(a1.s, bfr[1], acc, 0, 0, 0);
        acc = __builtin_amdgcn_mfma_f32_16x16x32_bf16(a2.s, bfr[2], acc, 0, 0, 0);
        // D: col = lane&15 (=output o), row = quad*4 + i (task within tile)
        if (nn < 8) {
            #pragma unroll
            for (int i = 0; i < 4; ++i) {
                int trow = t * 16 + quad * 4 + i;
                s_h[trow * 8 + nn] = f2bf(crelu(acc[i]));
            }
        }
    }
    __syncthreads();

    // ---- phase 2: layers 2 (8->8) and 3 (8->1), fp32, thread-per-task ----
    #pragma unroll 1
    for (int task = tid; task < BT * 36; task += 256) {
        uint b = (uint)task / 36u;
        uint p = (uint)task - 36u * b;
        const uint4* hp = (const uint4*)s_h;
        uint4 hv = hp[task];                    // 8 bf16, one b128
        float h[8];
        h[0] = __uint_as_float(hv.x << 16);
        h[1] = __uint_as_float(hv.x & 0xffff0000u);
        h[2] = __uint_as_float(hv.y << 16);
        h[3] = __uint_as_float(hv.y & 0xffff0000u);
        h[4] = __uint_as_float(hv.z << 16);
        h[5] = __uint_as_float(hv.z & 0xffff0000u);
        h[6] = __uint_as_float(hv.w << 16);
        h[7] = __uint_as_float(hv.w & 0xffff0000u);

        float a2[8];
        #pragma unroll
        for (int o = 0; o < 8; ++o) a2[o] = b2[o];
        #pragma unroll
        for (int i = 0; i < 8; ++i) {
            #pragma unroll
            for (int o = 0; o < 8; ++o)
                a2[o] = fmaf(h[i], W2[i * 8 + o], a2[o]);
        }
        float v = b3[0];
        #pragma unroll
        for (int i = 0; i < 8; ++i) v = fmaf(crelu(a2[i]), W3[i], v);
        s_vis[b * 37 + p] = crelu(v);
    }
    if (tid < BT) s_vis[tid * 37 + 36] = s_cen[tid];
    __syncthreads();

    // ---- phase 3: vision head 37->16->16->1 ----
    #pragma unroll
    for (int rep = 0; rep < 2; ++rep) {
        int t = tid + rep * 256;
        int b = t & 31, o = t >> 5;
        float a = c1[o];
        #pragma unroll
        for (int f = 0; f < 37; ++f)
            a = fmaf(s_vis[b * 37 + f], E1[f * 16 + o], a);
        s_g1[b * 17 + o] = crelu(a);
    }
    __syncthreads();
    #pragma unroll
    for (int rep = 0; rep < 2; ++rep) {
        int t = tid + rep * 256;
        int b = t & 31, o = t >> 5;
        float a = c2[o];
        #pragma unroll
        for (int f = 0; f < 16; ++f)
            a = fmaf(s_g1[b * 17 + f], E2[f * 16 + o], a);
        s_g2[b * 17 + o] = crelu(a);
    }
    __syncthreads();
    if (tid < BT) {
        float a = c3[0];
        #pragma unroll
        for (int f = 0; f < 16; ++f)
            a = fmaf(s_g2[tid * 17 + f], E3[f], a);
        out[b0 + tid] = crelu(a);
    }
}

extern "C" void kernel_launch(void* const* d_in, const int* in_sizes, int n_in,
                              void* d_out, int out_size, void* d_ws, size_t ws_size,
                              hipStream_t stream)
{
    const float* inp = (const float*)d_in[0];
    const float* W1  = (const float*)d_in[1];
    const float* b1  = (const float*)d_in[2];
    const float* W2  = (const float*)d_in[3];
    const float* b2  = (const float*)d_in[4];
    const float* W3  = (const float*)d_in[5];
    const float* b3  = (const float*)d_in[6];
    const float* E1  = (const float*)d_in[7];
    const float* c1  = (const float*)d_in[8];
    const float* E2  = (const float*)d_in[9];
    const float* c2  = (const float*)d_in[10];
    const float* E3  = (const float*)d_in[11];
    const float* c3  = (const float*)d_in[12];
    float* out = (float*)d_out;

    int B = in_sizes[0] / ROW;           // 131072
    int grid = B / BT;                   // 4096 blocks
    lila_mfma<<<grid, 256, 0, stream>>>(inp, W1, b1, W2, b2, W3, b3,
                                        E1, c1, E2, c2, E3, c3, out);
}

// Round 3
// 315.899 us; speedup vs baseline: 1.3198x; 1.1052x over previous
//
#include <hip/hip_runtime.h>

typedef __attribute__((ext_vector_type(8))) short short8;
typedef __attribute__((ext_vector_type(4))) float float4v;

__device__ __forceinline__ float crelu(float v) {
    return fminf(1.0f, fmaxf(-1.0f, v));
}
// fp32 -> bf16 bits, round-to-nearest-even (inputs finite)
__device__ __forceinline__ ushort f2bf(float v) {
    uint u = __float_as_uint(v);
    u += 0x7fffu + ((u >> 16) & 1u);
    return (ushort)(u >> 16);
}

#define ROW 385
#define BT 16
#define BS 388                      // board row stride in bf16 elems (even)
#define BOARD_ELEMS (BT * BS)       // 6208
#define BOARD_TOTAL (BOARD_ELEMS + 64)

__global__ __launch_bounds__(256, 6)
void lila_mfma(const float* __restrict__ inp,
               const float* __restrict__ W1, const float* __restrict__ b1,
               const float* __restrict__ W2, const float* __restrict__ b2,
               const float* __restrict__ W3, const float* __restrict__ b3,
               const float* __restrict__ E1, const float* __restrict__ c1,
               const float* __restrict__ E2, const float* __restrict__ c2,
               const float* __restrict__ E3, const float* __restrict__ c3,
               float* __restrict__ out)
{
    __shared__ __align__(16) ushort s_board[BOARD_TOTAL]; // 12544 B
    __shared__ __align__(16) ushort s_h[BT * 36 * 8];     // 9216 B
    __shared__ float s_vis[BT * 37];                      // 2368 B
    __shared__ float s_cen[BT];
    __shared__ float s_g1[BT * 17];
    __shared__ float s_g2[BT * 17];

    const int tid  = threadIdx.x;
    const int lane = tid & 63;
    const int wv   = tid >> 6;
    const int quad = lane >> 4;
    const int nn   = tid & 15;
    const int m0   = quad * 8;
    const long long b0 = (long long)blockIdx.x * BT;

    // ---- B fragments for layer-1 MFMA (3 K-runs of 18, zero-padded to 32) ----
    // B[k][n]: n = lane&15, k = quad*8 + j. n>=8 or k>=18 -> 0.
    short8 bfr[3];
    #pragma unroll
    for (int r = 0; r < 3; ++r) {
        #pragma unroll
        for (int j = 0; j < 8; ++j) {
            int k = m0 + j;
            float w = (k < 18 && nn < 8) ? W1[(r * 18 + k) * 8 + nn] : 0.0f;
            bfr[r][j] = (short)f2bf(w);
        }
    }
    const float bias1 = (nn < 8) ? b1[nn] : 0.0f;

    // ---- stage 16 input rows -> bf16 board in LDS (4 rows per wave) ----
    #pragma unroll 1
    for (int rr = 0; rr < 4; ++rr) {
        int row = wv * 4 + rr;
        const float* gr = inp + (b0 + row) * ROW;
        ushort* br = s_board + row * BS;
        #pragma unroll
        for (int s = 0; s < 6; ++s)
            br[lane + 64 * s] = f2bf(gr[lane + 64 * s]);
        if (lane == 0) s_cen[row] = gr[384];
        if (lane < 4)  br[384 + lane] = 0;   // zero row pad (finite-garbage safety)
    }
    if (tid < 64) s_board[BOARD_ELEMS + tid] = 0; // zero tail pad
    __syncthreads();

    // ---- phase 1: layer 1 (54->8) via bf16 MFMA, 36 tiles of 16 tasks ----
    #pragma unroll 1
    for (int t = wv; t < 36; t += 4) {
        int task = t * 16 + nn;                 // A row m = lane&15
        uint b = (uint)task / 36u;
        uint p = (uint)task - 36u * b;
        uint x = p / 6u;
        uint y = p - 6u * x;
        const uint* bp = (const uint*)(s_board + b * BS + x * 48 + 6 * y + m0);
        union { uint u[4]; short8 s; } a0, a1, a2;
        #pragma unroll
        for (int q = 0; q < 4; ++q) {
            a0.u[q] = bp[q];        // run 0: +0 elems
            a1.u[q] = bp[24 + q];   // run 1: +48 elems
            a2.u[q] = bp[48 + q];   // run 2: +96 elems
        }
        float4v acc = { bias1, bias1, bias1, bias1 };
        acc = __builtin_amdgcn_mfma_f32_16x16x32_bf16(a0.s, bfr[0], acc, 0, 0, 0);
        acc = __builtin_amdgcn_mfma_f32_16x16x32_bf16(a1.s, bfr[1], acc, 0, 0, 0);
        acc = __builtin_amdgcn_mfma_f32_16x16x32_bf16(a2.s, bfr[2], acc, 0, 0, 0);
        // D: col = lane&15 (=output o), row = quad*4 + i (task within tile)
        if (nn < 8) {
            #pragma unroll
            for (int i = 0; i < 4; ++i) {
                int trow = t * 16 + quad * 4 + i;
                s_h[trow * 8 + nn] = f2bf(crelu(acc[i]));
            }
        }
    }
    __syncthreads();

    // ---- phase 2: layers 2 (8->8) and 3 (8->1), fp32, thread-per-task ----
    #pragma unroll 1
    for (int task = tid; task < BT * 36; task += 256) {
        uint b = (uint)task / 36u;
        uint p = (uint)task - 36u * b;
        const uint4* hp = (const uint4*)s_h;
        uint4 hv = hp[task];                    // 8 bf16, one b128
        float h[8];
        h[0] = __uint_as_float(hv.x << 16);
        h[1] = __uint_as_float(hv.x & 0xffff0000u);
        h[2] = __uint_as_float(hv.y << 16);
        h[3] = __uint_as_float(hv.y & 0xffff0000u);
        h[4] = __uint_as_float(hv.z << 16);
        h[5] = __uint_as_float(hv.z & 0xffff0000u);
        h[6] = __uint_as_float(hv.w << 16);
        h[7] = __uint_as_float(hv.w & 0xffff0000u);

        float a2[8];
        #pragma unroll
        for (int o = 0; o < 8; ++o) a2[o] = b2[o];
        #pragma unroll
        for (int i = 0; i < 8; ++i) {
            #pragma unroll
            for (int o = 0; o < 8; ++o)
                a2[o] = fmaf(h[i], W2[i * 8 + o], a2[o]);
        }
        float v = b3[0];
        #pragma unroll
        for (int i = 0; i < 8; ++i) v = fmaf(crelu(a2[i]), W3[i], v);
        s_vis[b * 37 + p] = crelu(v);
    }
    if (tid < BT) s_vis[tid * 37 + 36] = s_cen[tid];
    __syncthreads();

    // ---- phase 3: vision head 37->16->16->1 (one thread per (b,o)) ----
    {
        int b = tid & 15, o = tid >> 4;
        float a = c1[o];
        #pragma unroll
        for (int f = 0; f < 37; ++f)
            a = fmaf(s_vis[b * 37 + f], E1[f * 16 + o], a);
        s_g1[b * 17 + o] = crelu(a);
    }
    __syncthreads();
    {
        int b = tid & 15, o = tid >> 4;
        float a = c2[o];
        #pragma unroll
        for (int f = 0; f < 16; ++f)
            a = fmaf(s_g1[b * 17 + f], E2[f * 16 + o], a);
        s_g2[b * 17 + o] = crelu(a);
    }
    __syncthreads();
    if (tid < BT) {
        float a = c3[0];
        #pragma unroll
        for (int f = 0; f < 16; ++f)
            a = fmaf(s_g2[tid * 17 + f], E3[f], a);
        out[b0 + tid] = crelu(a);
    }
}

extern "C" void kernel_launch(void* const* d_in, const int* in_sizes, int n_in,
                              void* d_out, int out_size, void* d_ws, size_t ws_size,
                              hipStream_t stream)
{
    const float* inp = (const float*)d_in[0];
    const float* W1  = (const float*)d_in[1];
    const float* b1  = (const float*)d_in[2];
    const float* W2  = (const float*)d_in[3];
    const float* b2  = (const float*)d_in[4];
    const float* W3  = (const float*)d_in[5];
    const float* b3  = (const float*)d_in[6];
    const float* E1  = (const float*)d_in[7];
    const float* c1  = (const float*)d_in[8];
    const float* E2  = (const float*)d_in[9];
    const float* c2  = (const float*)d_in[10];
    const float* E3  = (const float*)d_in[11];
    const float* c3  = (const float*)d_in[12];
    float* out = (float*)d_out;

    int B = in_sizes[0] / ROW;           // 131072
    int grid = B / BT;                   // 8192 blocks
    lila_mfma<<<grid, 256, 0, stream>>>(inp, W1, b1, W2, b2, W3, b3,
                                        E1, c1, E2, c2, E3, c3, out);
}

// Round 4
// 300.549 us; speedup vs baseline: 1.3872x; 1.0511x over previous
//
#include <hip/hip_runtime.h>

typedef __attribute__((ext_vector_type(8))) short short8;
typedef __attribute__((ext_vector_type(4))) float float4v;

__device__ __forceinline__ float crelu(float v) {
    return fminf(1.0f, fmaxf(-1.0f, v));
}
// fp32 -> bf16 bits, round-to-nearest-even (finite inputs)
__device__ __forceinline__ uint f2bf_u(float v) {
    uint u = __float_as_uint(v);
    u += 0x7fffu + ((u >> 16) & 1u);
    return u >> 16;
}
__device__ __forceinline__ ushort f2bf(float v) { return (ushort)f2bf_u(v); }

#define ROW 385
#define BT  16            // samples per block (4 waves x 4 samples)
#define BS  388           // ushorts per board row in LDS (even)

// per-wave LDS slab (bytes):
//   [0,3104)    board: 4 x 388 ushort
//   [3104,3136) zeroed tail pad (16 ushort) -- phase-1 overread lands here
//   [3136,5440) h: 144 x 8 ushort (16B-aligned rows)
// aliases (board is dead after phase 1):
//   vis: float[4*40] @ 0      (written phase 2, read phase 3)
//   g1 : float[4*17] @ 640    (phase 3 internal)
#define SLAB_BYTES 5440

__global__ __launch_bounds__(256, 7)
void lila_wave(const float* __restrict__ inp,
               const float* __restrict__ W1, const float* __restrict__ b1,
               const float* __restrict__ W2, const float* __restrict__ b2,
               const float* __restrict__ W3, const float* __restrict__ b3,
               const float* __restrict__ E1, const float* __restrict__ c1,
               const float* __restrict__ E2, const float* __restrict__ c2,
               const float* __restrict__ E3, const float* __restrict__ c3,
               float* __restrict__ out)
{
    __shared__ __align__(16) char slab_all[4 * SLAB_BYTES];   // 21760 B

    const int tid  = threadIdx.x;
    const int lane = tid & 63;
    const int wv   = tid >> 6;
    const int quad = lane >> 4;
    const int nn   = lane & 15;
    const int m0   = quad * 8;

    char*   slab  = slab_all + wv * SLAB_BYTES;
    ushort* board = (ushort*)slab;
    ushort* hbuf  = (ushort*)(slab + 3136);
    float*  vis   = (float*)slab;           // alias of board region
    float*  g1    = (float*)(slab + 640);   // alias of board region

    const long long b0w = (long long)blockIdx.x * BT + wv * 4;  // wave's first sample

    // ---- B fragments for layer-1 MFMA (3 K-runs of 18, zero-padded to 32) ----
    // B[k][n]: n = lane&15, k = quad*8 + j. n>=8 or k>=18 -> 0.
    short8 bfr[3];
    #pragma unroll
    for (int r = 0; r < 3; ++r) {
        #pragma unroll
        for (int j = 0; j < 8; ++j) {
            int k = m0 + j;
            float w = (k < 18 && nn < 8) ? W1[(r * 18 + k) * 8 + nn] : 0.0f;
            bfr[r][j] = (short)f2bf(w);
        }
    }
    const float bias1 = (nn < 8) ? b1[nn] : 0.0f;

    // ---- stage this wave's 4 samples -> bf16 board (wave-private, no barrier) ----
    const int r   = lane >> 4;      // sample row within wave (0..3)
    const int c16 = lane & 15;
    const float* gr = inp + (b0w + r) * ROW;

    // zero the row pads (elems 384..387 per row) and the 16-short tail pad
    if (lane < 4) *(unsigned long long*)(board + lane * BS + 384) = 0ULL;
    if (lane >= 4 && lane < 8)
        *(unsigned long long*)(slab + 3104 + (lane - 4) * 8) = 0ULL;

    #pragma unroll
    for (int j = 0; j < 12; ++j) {
        int e = 2 * (c16 + 16 * j);                   // 0..382, even
        float f0 = gr[e], f1 = gr[e + 1];
        uint pk = f2bf_u(f0) | (f2bf_u(f1) << 16);
        *(uint*)((char*)board + r * 776 + 2 * e) = pk; // packed bf16x2
    }
    const float cen = gr[384];                        // this lane's board center

    asm volatile("" ::: "memory");   // keep staging writes before phase-1 reads

    // ---- phase 1: layer 1 (54->8) via bf16 MFMA, 9 tiles of 16 tasks ----
    #pragma unroll 1
    for (int t = 0; t < 9; ++t) {
        int ltask = t * 16 + nn;                 // A row m = lane&15
        uint lb = (uint)ltask / 36u;             // local sample 0..3
        uint p  = (uint)ltask - 36u * lb;
        uint x  = p / 6u;
        uint y  = p - 6u * x;
        const uint* bp = (const uint*)(board + lb * BS + x * 48 + 6 * y + m0);
        union { uint u[4]; short8 s; } a0, a1, a2;
        #pragma unroll
        for (int q = 0; q < 4; ++q) {
            a0.u[q] = bp[q];        // run 0
            a1.u[q] = bp[24 + q];   // run 1 (+48 elems)
            a2.u[q] = bp[48 + q];   // run 2 (+96 elems)
        }
        float4v acc = { bias1, bias1, bias1, bias1 };
        acc = __builtin_amdgcn_mfma_f32_16x16x32_bf16(a0.s, bfr[0], acc, 0, 0, 0);
        acc = __builtin_amdgcn_mfma_f32_16x16x32_bf16(a1.s, bfr[1], acc, 0, 0, 0);
        acc = __builtin_amdgcn_mfma_f32_16x16x32_bf16(a2.s, bfr[2], acc, 0, 0, 0);
        // D: col = lane&15 (=output o), row = quad*4 + i (task within tile)
        if (nn < 8) {
            #pragma unroll
            for (int i = 0; i < 4; ++i) {
                int trow = t * 16 + quad * 4 + i;
                hbuf[trow * 8 + nn] = f2bf(crelu(acc[i]));
            }
        }
    }

    asm volatile("" ::: "memory");   // board dead; vis writes may now target its bytes

    // ---- phase 2: layers 2 (8->8) + 3 (8->1), fp32, 144 tasks over 64 lanes ----
    #pragma unroll 1
    for (int it = 0; it < 3; ++it) {
        int task = lane + it * 64;
        if (task < 144) {
            uint lb = (uint)task / 36u;
            uint p  = (uint)task - 36u * lb;
            uint4 hv = *(const uint4*)(hbuf + task * 8);   // 8 bf16, one b128
            float h[8];
            h[0] = __uint_as_float(hv.x << 16);
            h[1] = __uint_as_float(hv.x & 0xffff0000u);
            h[2] = __uint_as_float(hv.y << 16);
            h[3] = __uint_as_float(hv.y & 0xffff0000u);
            h[4] = __uint_as_float(hv.z << 16);
            h[5] = __uint_as_float(hv.z & 0xffff0000u);
            h[6] = __uint_as_float(hv.w << 16);
            h[7] = __uint_as_float(hv.w & 0xffff0000u);

            float a2[8];
            #pragma unroll
            for (int o = 0; o < 8; ++o) a2[o] = b2[o];
            #pragma unroll
            for (int i = 0; i < 8; ++i) {
                #pragma unroll
                for (int o = 0; o < 8; ++o)
                    a2[o] = fmaf(h[i], W2[i * 8 + o], a2[o]);
            }
            float v = b3[0];
            #pragma unroll
            for (int i = 0; i < 8; ++i) v = fmaf(crelu(a2[i]), W3[i], v);
            vis[lb * 40 + p] = crelu(v);
        }
    }

    asm volatile("" ::: "memory");   // vis writes before phase-3 reads

    // ---- phase 3: vision head 37->16->16->1, lane = (sample r, output o) ----
    {
        const int o = nn;            // 0..15; sample index = r (== lane>>4)
        float a = c1[o];
        #pragma unroll
        for (int f = 0; f < 36; ++f)
            a = fmaf(vis[r * 40 + f], E1[f * 16 + o], a);
        a = fmaf(cen, E1[36 * 16 + o], a);
        g1[r * 17 + o] = crelu(a);

        asm volatile("" ::: "memory");

        float a2 = c2[o];
        #pragma unroll
        for (int f = 0; f < 16; ++f)
            a2 = fmaf(g1[r * 17 + f], E2[f * 16 + o], a2);
        float t = crelu(a2) * E3[o];
        // sum over the 16 lanes of this sample group
        t += __shfl_xor(t, 1);
        t += __shfl_xor(t, 2);
        t += __shfl_xor(t, 4);
        t += __shfl_xor(t, 8);
        if (o == 0) out[b0w + r] = crelu(t + c3[0]);
    }
}

extern "C" void kernel_launch(void* const* d_in, const int* in_sizes, int n_in,
                              void* d_out, int out_size, void* d_ws, size_t ws_size,
                              hipStream_t stream)
{
    const float* inp = (const float*)d_in[0];
    const float* W1  = (const float*)d_in[1];
    const float* b1  = (const float*)d_in[2];
    const float* W2  = (const float*)d_in[3];
    const float* b2  = (const float*)d_in[4];
    const float* W3  = (const float*)d_in[5];
    const float* b3  = (const float*)d_in[6];
    const float* E1  = (const float*)d_in[7];
    const float* c1  = (const float*)d_in[8];
    const float* E2  = (const float*)d_in[9];
    const float* c2  = (const float*)d_in[10];
    const float* E3  = (const float*)d_in[11];
    const float* c3  = (const float*)d_in[12];
    float* out = (float*)d_out;

    int B = in_sizes[0] / ROW;           // 131072
    int grid = B / BT;                   // 8192 blocks
    lila_wave<<<grid, 256, 0, stream>>>(inp, W1, b1, W2, b2, W3, b3,
                                        E1, c1, E2, c2, E3, c3, out);
}

// Round 5
// 298.873 us; speedup vs baseline: 1.3950x; 1.0056x over previous
//
#include <hip/hip_runtime.h>

typedef __attribute__((ext_vector_type(8))) short short8;
typedef __attribute__((ext_vector_type(4))) float float4v;

__device__ __forceinline__ float crelu(float v) {
    return fminf(1.0f, fmaxf(-1.0f, v));
}
// fp32 -> bf16 bits, round-to-nearest-even (finite inputs)
__device__ __forceinline__ uint f2bf_u(float v) {
    uint u = __float_as_uint(v);
    u += 0x7fffu + ((u >> 16) & 1u);
    return u >> 16;
}
__device__ __forceinline__ ushort f2bf(float v) { return (ushort)f2bf_u(v); }

#define ROW 385
#define BT  16            // samples per block = 4 waves x 4 samples

// per-wave LDS slab (bytes):
//   board: 4 samples x 544 ushort  = 4352 B @ 0
//          sample layout: 8 rows x 8 cells x 8 bf16 (6 data + 2 zero) = 512,
//          + 32 zeroed pad elems (512..543) absorbing all phase-1 overreads
//   hbuf : 144 tasks x 8 bf16      = 2304 B @ 4352
// aliases on dead board region after phase 1:
//   vis: f32[4][40] @ 0 (640 B) ; g1: f32[4][20] @ 640 (320 B)
#define SLAB_BYTES 6656

__global__ __launch_bounds__(256, 6)
void lila_wave(const float* __restrict__ inp,
               const float* __restrict__ W1, const float* __restrict__ b1,
               const float* __restrict__ W2, const float* __restrict__ b2,
               const float* __restrict__ W3, const float* __restrict__ b3,
               const float* __restrict__ E1, const float* __restrict__ c1,
               const float* __restrict__ E2, const float* __restrict__ c2,
               const float* __restrict__ E3, const float* __restrict__ c3,
               float* __restrict__ out)
{
    __shared__ __align__(16) char slab_all[4 * SLAB_BYTES];   // 26624 B

    const int tid  = threadIdx.x;
    const int lane = tid & 63;
    const int wv   = tid >> 6;
    const int quad = lane >> 4;
    const int nn   = lane & 15;
    const int m0   = quad * 8;

    char*   slab  = slab_all + wv * SLAB_BYTES;
    ushort* board = (ushort*)slab;
    ushort* hbuf  = (ushort*)(slab + 4352);
    float*  vis   = (float*)slab;           // alias of board (dead after phase 1)
    float*  g1    = (float*)(slab + 640);   // alias of board

    const long long b0w = (long long)blockIdx.x * BT + wv * 4;

    // ---- B fragments for layer-1 MFMA, remapped to padded-cell K layout ----
    // k = quad*8 + j ; cell oy = k>>3, within-cell c = k&7.
    // valid iff oy<3 && c<6 && n<8 ; pad/garbage positions get weight 0.
    short8 bfr[3];
    #pragma unroll
    for (int r = 0; r < 3; ++r) {
        #pragma unroll
        for (int j = 0; j < 8; ++j) {
            int k = m0 + j, oy = k >> 3, c = k & 7;
            float w = (oy < 3 && c < 6 && nn < 8)
                    ? W1[(r * 18 + oy * 6 + c) * 8 + nn] : 0.0f;
            bfr[r][j] = (short)f2bf(w);
        }
    }
    const float bias1 = (nn < 8) ? b1[nn] : 0.0f;

    // ---- stage 4 samples -> padded bf16 board, 16B-granular writes ----
    const int r   = lane >> 4;          // sample within wave
    const int c16 = lane & 15;
    const float* gr = inp + (b0w + r) * ROW;

    if (c16 < 4) {                      // zero the 64B tail pad (elems 512..543)
        uint4 z = {0u, 0u, 0u, 0u};
        *(uint4*)(board + r * 544 + 512 + c16 * 8) = z;
    }
    #pragma unroll
    for (int u = 0; u < 4; ++u) {
        int cell = c16 + 16 * u;                   // 0..63
        int X = cell >> 3, Y = cell & 7;
        int g = X * 48 + Y * 6;                    // even -> 8B-aligned loads
        float2 p0 = *(const float2*)(gr + g);
        float2 p1 = *(const float2*)(gr + g + 2);
        float2 p2 = *(const float2*)(gr + g + 4);
        uint4 pk;
        pk.x = f2bf_u(p0.x) | (f2bf_u(p0.y) << 16);
        pk.y = f2bf_u(p1.x) | (f2bf_u(p1.y) << 16);
        pk.z = f2bf_u(p2.x) | (f2bf_u(p2.y) << 16);
        pk.w = 0u;                                 // cell pad (zero weights anyway)
        *(uint4*)(board + r * 544 + cell * 8) = pk;
    }
    const float cen = gr[384];

    asm volatile("" ::: "memory");   // staging writes before phase-1 reads

    // ---- phase 1: layer 1 (54->8) via bf16 MFMA; A-frag = 3x ds_read_b128 ----
    #pragma unroll 1
    for (int t = 0; t < 9; ++t) {
        int ltask = t * 16 + nn;
        uint lb = (uint)ltask / 36u;
        uint p  = (uint)ltask - 36u * lb;
        uint x  = p / 6u;
        uint y  = p - 6u * x;
        // run r: row (x+r), elems 8y + k ; lane reads 8 elems at +m0 (16B-aligned)
        const ushort* base = board + lb * 544 + x * 64 + 8 * y + m0;
        union { uint4 u; short8 s; } a0, a1, a2;
        a0.u = *(const uint4*)(base);         // row x
        a1.u = *(const uint4*)(base + 64);    // row x+1
        a2.u = *(const uint4*)(base + 128);   // row x+2
        float4v acc = { bias1, bias1, bias1, bias1 };
        acc = __builtin_amdgcn_mfma_f32_16x16x32_bf16(a0.s, bfr[0], acc, 0, 0, 0);
        acc = __builtin_amdgcn_mfma_f32_16x16x32_bf16(a1.s, bfr[1], acc, 0, 0, 0);
        acc = __builtin_amdgcn_mfma_f32_16x16x32_bf16(a2.s, bfr[2], acc, 0, 0, 0);
        // D: col = nn (=output o), row = quad*4 + i (task within tile)
        if (nn < 8) {
            #pragma unroll
            for (int i = 0; i < 4; ++i)
                hbuf[(t * 16 + quad * 4 + i) * 8 + nn] = f2bf(crelu(acc[i]));
        }
    }

    asm volatile("" ::: "memory");   // board dead; vis may alias its bytes now

    // ---- phase 2: layers 2 (8->8) + 3 (8->1), fp32, 144 tasks ----
    #pragma unroll 1
    for (int it = 0; it < 3; ++it) {
        int task = lane + it * 64;
        if (task < 144) {
            uint lb = (uint)task / 36u;
            uint p  = (uint)task - 36u * lb;
            uint4 hv = *(const uint4*)(hbuf + task * 8);   // one b128
            float h[8];
            h[0] = __uint_as_float(hv.x << 16);
            h[1] = __uint_as_float(hv.x & 0xffff0000u);
            h[2] = __uint_as_float(hv.y << 16);
            h[3] = __uint_as_float(hv.y & 0xffff0000u);
            h[4] = __uint_as_float(hv.z << 16);
            h[5] = __uint_as_float(hv.z & 0xffff0000u);
            h[6] = __uint_as_float(hv.w << 16);
            h[7] = __uint_as_float(hv.w & 0xffff0000u);

            float a2[8];
            #pragma unroll
            for (int o = 0; o < 8; ++o) a2[o] = b2[o];
            #pragma unroll
            for (int i = 0; i < 8; ++i) {
                #pragma unroll
                for (int o = 0; o < 8; ++o)
                    a2[o] = fmaf(h[i], W2[i * 8 + o], a2[o]);
            }
            float v = b3[0];
            #pragma unroll
            for (int i = 0; i < 8; ++i) v = fmaf(crelu(a2[i]), W3[i], v);
            vis[lb * 40 + p] = crelu(v);
        }
    }

    asm volatile("" ::: "memory");   // vis writes before phase-3 reads

    // ---- phase 3: vision head 37->16->16->1 ; lane = (sample r, output nn) ----
    {
        const int o = nn;
        float a = c1[o];
        #pragma unroll
        for (int fi = 0; fi < 9; ++fi) {       // 36 floats as 9 broadcast b128
            float4 vv = *(const float4*)(vis + r * 40 + fi * 4);
            a = fmaf(vv.x, E1[(fi * 4 + 0) * 16 + o], a);
            a = fmaf(vv.y, E1[(fi * 4 + 1) * 16 + o], a);
            a = fmaf(vv.z, E1[(fi * 4 + 2) * 16 + o], a);
            a = fmaf(vv.w, E1[(fi * 4 + 3) * 16 + o], a);
        }
        a = fmaf(cen, E1[36 * 16 + o], a);
        g1[r * 20 + o] = crelu(a);

        asm volatile("" ::: "memory");

        float a2 = c2[o];
        #pragma unroll
        for (int fi = 0; fi < 4; ++fi) {       // 16 floats as 4 broadcast b128
            float4 gv = *(const float4*)(g1 + r * 20 + fi * 4);
            a2 = fmaf(gv.x, E2[(fi * 4 + 0) * 16 + o], a2);
            a2 = fmaf(gv.y, E2[(fi * 4 + 1) * 16 + o], a2);
            a2 = fmaf(gv.z, E2[(fi * 4 + 2) * 16 + o], a2);
            a2 = fmaf(gv.w, E2[(fi * 4 + 3) * 16 + o], a2);
        }
        float tv = crelu(a2) * E3[o];
        tv += __shfl_xor(tv, 1);
        tv += __shfl_xor(tv, 2);
        tv += __shfl_xor(tv, 4);
        tv += __shfl_xor(tv, 8);
        if (o == 0) out[b0w + r] = crelu(tv + c3[0]);
    }
}

extern "C" void kernel_launch(void* const* d_in, const int* in_sizes, int n_in,
                              void* d_out, int out_size, void* d_ws, size_t ws_size,
                              hipStream_t stream)
{
    const float* inp = (const float*)d_in[0];
    const float* W1  = (const float*)d_in[1];
    const float* b1  = (const float*)d_in[2];
    const float* W2  = (const float*)d_in[3];
    const float* b2  = (const float*)d_in[4];
    const float* W3  = (const float*)d_in[5];
    const float* b3  = (const float*)d_in[6];
    const float* E1  = (const float*)d_in[7];
    const float* c1  = (const float*)d_in[8];
    const float* E2  = (const float*)d_in[9];
    const float* c2  = (const float*)d_in[10];
    const float* E3  = (const float*)d_in[11];
    const float* c3  = (const float*)d_in[12];
    float* out = (float*)d_out;

    int B = in_sizes[0] / ROW;           // 131072
    int grid = B / BT;                   // 8192 blocks
    lila_wave<<<grid, 256, 0, stream>>>(inp, W1, b1, W2, b2, W3, b3,
                                        E1, c1, E2, c2, E3, c3, out);
}

// Round 6
// 291.928 us; speedup vs baseline: 1.4282x; 1.0238x over previous
//
#include <hip/hip_runtime.h>

typedef __attribute__((ext_vector_type(8))) short short8;
typedef __attribute__((ext_vector_type(4))) float float4v;

__device__ __forceinline__ float crelu(float v) {
    return fminf(1.0f, fmaxf(-1.0f, v));
}
// fp32 -> bf16 bits, round-to-nearest-even (finite inputs)
__device__ __forceinline__ uint f2bf_u(float v) {
    uint u = __float_as_uint(v);
    u += 0x7fffu + ((u >> 16) & 1u);
    return u >> 16;
}
__device__ __forceinline__ ushort f2bf(float v) { return (ushort)f2bf_u(v); }
__device__ __forceinline__ float bf2f_lo(uint u) { return __uint_as_float(u << 16); }
__device__ __forceinline__ float bf2f_hi(uint u) { return __uint_as_float(u & 0xffff0000u); }

#define ROW 385
#define BT  16            // samples per block = 4 waves x 4 samples

// per-wave LDS slab (bytes):
//   board: 4 samples x 544 ushort = 4352 B @ 0
//          sample: 8 rows x 8 cells x 8 bf16 (6 data + 2 zero) + 32 pad elems
//   hbuf : 144 tasks x 8 bf16     = 2304 B @ 4352
// aliases on dead board region after phase 1:
//   vis : f32[4][40]   @ 0     (640 B)
//   g1  : f32[4][20]   @ 640   (320 B)
//   E1T : f32[16][40]  @ 1024  (2560 B)   E1 transposed, o-major (37 used)
//   E2T : bf16[16][16] @ 3584  (512 B)    E2 transposed, o-major
#define SLAB_BYTES 6656
#define E1T_OFF 1024
#define E2T_OFF 3584

__global__ __launch_bounds__(256, 6)
void lila_wave(const float* __restrict__ inp,
               const float* __restrict__ W1, const float* __restrict__ b1,
               const float* __restrict__ W2, const float* __restrict__ b2,
               const float* __restrict__ W3, const float* __restrict__ b3,
               const float* __restrict__ E1, const float* __restrict__ c1,
               const float* __restrict__ E2, const float* __restrict__ c2,
               const float* __restrict__ E3, const float* __restrict__ c3,
               float* __restrict__ out)
{
    __shared__ __align__(16) char slab_all[4 * SLAB_BYTES];   // 26624 B

    const int tid  = threadIdx.x;
    const int lane = tid & 63;
    const int wv   = tid >> 6;
    const int quad = lane >> 4;
    const int nn   = lane & 15;
    const int m0   = quad * 8;

    char*   slab  = slab_all + wv * SLAB_BYTES;
    ushort* board = (ushort*)slab;
    ushort* hbuf  = (ushort*)(slab + 4352);
    float*  vis   = (float*)slab;
    float*  g1    = (float*)(slab + 640);
    float*  e1t   = (float*)(slab + E1T_OFF);
    ushort* e2t   = (ushort*)(slab + E2T_OFF);

    const long long b0w = (long long)blockIdx.x * BT + wv * 4;

    // ---- B fragments for layer-1 MFMA, padded-cell K layout ----
    // k = quad*8 + j ; cell oy = k>>3, within-cell c = k&7.
    short8 bfr[3];
    #pragma unroll
    for (int r = 0; r < 3; ++r) {
        #pragma unroll
        for (int j = 0; j < 8; ++j) {
            int k = m0 + j, oy = k >> 3, c = k & 7;
            float w = (oy < 3 && c < 6 && nn < 8)
                    ? W1[(r * 18 + oy * 6 + c) * 8 + nn] : 0.0f;
            bfr[r][j] = (short)f2bf(w);
        }
    }
    const float bias1 = (nn < 8) ? b1[nn] : 0.0f;

    // ---- stage 4 samples -> padded bf16 board, 16B writes ----
    const int r   = lane >> 4;          // sample within wave
    const int c16 = lane & 15;
    const float* gr = inp + (b0w + r) * ROW;

    if (c16 < 4) {
        uint4 z = {0u, 0u, 0u, 0u};
        *(uint4*)(board + r * 544 + 512 + c16 * 8) = z;
    }
    #pragma unroll
    for (int u = 0; u < 4; ++u) {
        int cell = c16 + 16 * u;
        int g = cell * 6;
        float2 p0 = *(const float2*)(gr + g);
        float2 p1 = *(const float2*)(gr + g + 2);
        float2 p2 = *(const float2*)(gr + g + 4);
        uint4 pk;
        pk.x = f2bf_u(p0.x) | (f2bf_u(p0.y) << 16);
        pk.y = f2bf_u(p1.x) | (f2bf_u(p1.y) << 16);
        pk.z = f2bf_u(p2.x) | (f2bf_u(p2.y) << 16);
        pk.w = 0u;
        *(uint4*)(board + r * 544 + cell * 8) = pk;
    }
    const float cen = gr[384];

    asm volatile("" ::: "memory");   // staging writes before phase-1 reads

    // ---- phase 1: layer 1 (54->8) via bf16 MFMA; unroll 3 for LDS-latency ILP ----
    #pragma unroll 3
    for (int t = 0; t < 9; ++t) {
        int ltask = t * 16 + nn;
        uint lb = (uint)ltask / 36u;
        uint p  = (uint)ltask - 36u * lb;
        uint x  = p / 6u;
        uint y  = p - 6u * x;
        const ushort* base = board + lb * 544 + x * 64 + 8 * y + m0;
        union { uint4 u; short8 s; } a0, a1, a2;
        a0.u = *(const uint4*)(base);
        a1.u = *(const uint4*)(base + 64);
        a2.u = *(const uint4*)(base + 128);
        float4v acc = { bias1, bias1, bias1, bias1 };
        acc = __builtin_amdgcn_mfma_f32_16x16x32_bf16(a0.s, bfr[0], acc, 0, 0, 0);
        acc = __builtin_amdgcn_mfma_f32_16x16x32_bf16(a1.s, bfr[1], acc, 0, 0, 0);
        acc = __builtin_amdgcn_mfma_f32_16x16x32_bf16(a2.s, bfr[2], acc, 0, 0, 0);
        if (nn < 8) {
            #pragma unroll
            for (int i = 0; i < 4; ++i)
                hbuf[(t * 16 + quad * 4 + i) * 8 + nn] = f2bf(crelu(acc[i]));
        }
    }

    asm volatile("" ::: "memory");   // phase-1 board reads done; board now dead

    // ---- E-stage: wave-private E1T (f32) + E2T (bf16) into dead board region ----
    // E1 flat j = lane + 64k -> f = r + 4k, o = nn  (j < 592)
    {
        float e1g[10];
        #pragma unroll
        for (int k = 0; k < 9; ++k) e1g[k] = E1[lane + 64 * k];
        if (lane < 16) e1g[9] = E1[lane + 576];
        float e2g[4];
        #pragma unroll
        for (int k = 0; k < 4; ++k) e2g[k] = E2[lane + 64 * k];

        #pragma unroll
        for (int k = 0; k < 9; ++k) e1t[nn * 40 + r + 4 * k] = e1g[k];
        if (lane < 16) e1t[nn * 40 + 36] = e1g[9];
        #pragma unroll
        for (int k = 0; k < 4; ++k) e2t[nn * 16 + r + 4 * k] = f2bf(e2g[k]);
    }
    const float c1v = c1[nn];
    const float c2v = c2[nn];
    const float e3v = E3[nn];

    asm volatile("" ::: "memory");

    // ---- phase 2: layers 2 (8->8) + 3 (8->1), fp32, 144 tasks ----
    #pragma unroll 1
    for (int it = 0; it < 3; ++it) {
        int task = lane + it * 64;
        if (task < 144) {
            uint lb = (uint)task / 36u;
            uint p  = (uint)task - 36u * lb;
            uint4 hv = *(const uint4*)(hbuf + task * 8);
            float h[8];
            h[0] = bf2f_lo(hv.x); h[1] = bf2f_hi(hv.x);
            h[2] = bf2f_lo(hv.y); h[3] = bf2f_hi(hv.y);
            h[4] = bf2f_lo(hv.z); h[5] = bf2f_hi(hv.z);
            h[6] = bf2f_lo(hv.w); h[7] = bf2f_hi(hv.w);

            float a2[8];
            #pragma unroll
            for (int o = 0; o < 8; ++o) a2[o] = b2[o];
            #pragma unroll
            for (int i = 0; i < 8; ++i) {
                #pragma unroll
                for (int o = 0; o < 8; ++o)
                    a2[o] = fmaf(h[i], W2[i * 8 + o], a2[o]);
            }
            float v = b3[0];
            #pragma unroll
            for (int i = 0; i < 8; ++i) v = fmaf(crelu(a2[i]), W3[i], v);
            vis[lb * 40 + p] = crelu(v);
        }
    }

    asm volatile("" ::: "memory");   // vis + E-tables written before phase-3 reads

    // ---- phase 3: vision head 37->16->16->1 ; lane = (sample r, output nn) ----
    {
        const int o = nn;
        float a = c1v;
        #pragma unroll
        for (int fi = 0; fi < 9; ++fi) {
            float4 vv = *(const float4*)(vis + r * 40 + fi * 4);
            float4 ev = *(const float4*)(e1t + o * 40 + fi * 4);
            a = fmaf(vv.x, ev.x, a);
            a = fmaf(vv.y, ev.y, a);
            a = fmaf(vv.z, ev.z, a);
            a = fmaf(vv.w, ev.w, a);
        }
        a = fmaf(cen, e1t[o * 40 + 36], a);
        g1[r * 20 + o] = crelu(a);

        asm volatile("" ::: "memory");

        uint4 e2a = *(const uint4*)(e2t + o * 16);      // 16 bf16 weights
        uint4 e2b = *(const uint4*)(e2t + o * 16 + 8);
        float a2 = c2v;
        #pragma unroll
        for (int fi = 0; fi < 4; ++fi) {
            float4 gv = *(const float4*)(g1 + r * 20 + fi * 4);
            uint w01 = (fi < 2) ? (fi == 0 ? e2a.x : e2a.z) : (fi == 2 ? e2b.x : e2b.z);
            uint w23 = (fi < 2) ? (fi == 0 ? e2a.y : e2a.w) : (fi == 2 ? e2b.y : e2b.w);
            a2 = fmaf(gv.x, bf2f_lo(w01), a2);
            a2 = fmaf(gv.y, bf2f_hi(w01), a2);
            a2 = fmaf(gv.z, bf2f_lo(w23), a2);
            a2 = fmaf(gv.w, bf2f_hi(w23), a2);
        }
        float tv = crelu(a2) * e3v;
        tv += __shfl_xor(tv, 1);
        tv += __shfl_xor(tv, 2);
        tv += __shfl_xor(tv, 4);
        tv += __shfl_xor(tv, 8);
        if (o == 0) out[b0w + r] = crelu(tv + c3[0]);
    }
}

extern "C" void kernel_launch(void* const* d_in, const int* in_sizes, int n_in,
                              void* d_out, int out_size, void* d_ws, size_t ws_size,
                              hipStream_t stream)
{
    const float* inp = (const float*)d_in[0];
    const float* W1  = (const float*)d_in[1];
    const float* b1  = (const float*)d_in[2];
    const float* W2  = (const float*)d_in[3];
    const float* b2  = (const float*)d_in[4];
    const float* W3  = (const float*)d_in[5];
    const float* b3  = (const float*)d_in[6];
    const float* E1  = (const float*)d_in[7];
    const float* c1  = (const float*)d_in[8];
    const float* E2  = (const float*)d_in[9];
    const float* c2  = (const float*)d_in[10];
    const float* E3  = (const float*)d_in[11];
    const float* c3  = (const float*)d_in[12];
    float* out = (float*)d_out;

    int B = in_sizes[0] / ROW;           // 131072
    int grid = B / BT;                   // 8192 blocks
    lila_wave<<<grid, 256, 0, stream>>>(inp, W1, b1, W2, b2, W3, b3,
                                        E1, c1, E2, c2, E3, c3, out);
}